// Round 3
// baseline (285.792 us; speedup 1.0000x reference)
//
#include <hip/hip_runtime.h>

typedef __attribute__((ext_vector_type(8))) short short8;
typedef __attribute__((ext_vector_type(4))) float float4_;

__device__ __forceinline__ unsigned short f2bf(float f) {
    unsigned u = __float_as_uint(f);
    u += 0x7FFFu + ((u >> 16) & 1u);   // round-to-nearest-even
    return (unsigned short)(u >> 16);
}

#define GARF_BLOCKS 1536   // G(24) * C(64)
#define PREP_BLOCKS 2784   // ceil(712704 / 256)
#define XV_BLOCKS   6444   // 103104*128/8/256 (exact)

// ---------------------------------------------------------------------------
// Fused kernel 0: (a) ROI-align 32x32 bilinear patch means -> garfb[G][C] bf16
//                 (b) weights fp32 -> bf16, transposed to [N][K]
//                 (c) x_verts fp32 -> bf16 copy (so moe stages pure bf16)
// All three id-ranges are independent; (c) is pure streaming and overlaps
// the latency-bound (a)/(b) blocks.
// ---------------------------------------------------------------------------
__global__ void prep_garf(const float* __restrict__ imgs,
                          const float* __restrict__ pros,
                          const int* __restrict__ imgbatch,
                          const float* __restrict__ W1,
                          const float* __restrict__ W2,
                          const float* __restrict__ W3,
                          const float* __restrict__ x_verts,
                          unsigned short* __restrict__ w1t,
                          unsigned short* __restrict__ w2t,
                          unsigned short* __restrict__ w3t,
                          unsigned short* __restrict__ garfb,
                          unsigned short* __restrict__ xvb) {
    const int tid = threadIdx.x;
    if (blockIdx.x < GARF_BLOCKS) {
        __shared__ float part[4];
        int pc = blockIdx.x;
        int g = pc >> 6, c = pc & 63;
        int b = imgbatch[g];
        float cx = pros[g * 2 + 0], cy = pros[g * 2 + 1];
        int i = tid >> 3;                 // row 0..31
        int j0 = (tid & 7) * 4;           // 4 columns per thread
        float y = cy - 16.0f + (float)i + 0.5f;
        float yf = floorf(y);
        float wy1 = y - yf, wy0 = 1.0f - wy1;
        int iy0 = min(max((int)yf, 0), 191), iy1 = min(max((int)yf + 1, 0), 191);
        const float* base = imgs + (size_t)(b * 64 + c) * 36864;
        const float* r0 = base + iy0 * 192;
        const float* r1 = base + iy1 * 192;
        float sum = 0.0f;
#pragma unroll
        for (int jj = 0; jj < 4; ++jj) {
            float x = cx - 16.0f + (float)(j0 + jj) + 0.5f;
            float xf = floorf(x);
            float wx1 = x - xf, wx0 = 1.0f - wx1;
            int ix0 = min(max((int)xf, 0), 191), ix1 = min(max((int)xf + 1, 0), 191);
            sum += wy0 * (wx0 * r0[ix0] + wx1 * r0[ix1]) +
                   wy1 * (wx0 * r1[ix0] + wx1 * r1[ix1]);
        }
        for (int s = 32; s >= 1; s >>= 1) sum += __shfl_xor(sum, s);
        if ((tid & 63) == 0) part[tid >> 6] = sum;
        __syncthreads();
        if (tid == 0)
            garfb[pc] = f2bf((part[0] + part[1] + part[2] + part[3]) * (1.0f / 1024.0f));
    } else if (blockIdx.x < GARF_BLOCKS + PREP_BLOCKS) {
        int id = (blockIdx.x - GARF_BLOCKS) * 256 + tid;
        if (id < 294912) {                       // W1: 6*192*256, src [t][k][n]
            int t = id / 49152, r = id % 49152;
            int k = r >> 8, n = r & 255;
            w1t[t * 49152 + n * 192 + k] = f2bf(W1[id]);
        } else if (id < 688128) {                // W2: 6*256*256
            int i2 = id - 294912;
            int t = i2 >> 16, r = i2 & 65535;
            int k = r >> 8, n = r & 255;
            w2t[t * 65536 + n * 256 + k] = f2bf(W2[i2]);
        } else if (id < 712704) {                // w3t dest: 6*16*256 (n>=3 zero)
            int i3 = id - 688128;
            int t = i3 >> 12, r = i3 & 4095;
            int n = r >> 8, k = r & 255;
            w3t[i3] = (n < 3) ? f2bf(W3[t * 768 + k * 3 + n]) : (unsigned short)0;
        }
    } else {                                     // x_verts f32 -> bf16, streaming
        size_t uidx = (size_t)(blockIdx.x - GARF_BLOCKS - PREP_BLOCKS) * 256 + tid;
        const float4* src = (const float4*)(x_verts + uidx * 8);
        float4 v0 = src[0];
        float4 v1 = src[1];
        short8 pk;
        pk[0] = f2bf(v0.x); pk[1] = f2bf(v0.y); pk[2] = f2bf(v0.z); pk[3] = f2bf(v0.w);
        pk[4] = f2bf(v1.x); pk[5] = f2bf(v1.y); pk[6] = f2bf(v1.z); pk[7] = f2bf(v1.w);
        ((short8*)xvb)[uidx] = pk;
    }
}

// ---------------------------------------------------------------------------
// Kernel 1: fused MoE MLP (R0 structure: one 64-vertex tile per 256-thread
// block, max block-level TLP — pipelining variants measured slower).
// Changes vs R0: staging is a pure bf16 16B-copy gather (conversion moved to
// prep), and the idx/gar pre-stage barrier is gone (threads chase idx->gar
// directly; L2-hot). feat and hidden share one aliased 32KB LDS buffer.
// MFMA 16x16x32 bf16: A=weights[N][K], B=vertices; D register dim runs along
// the hidden dim -> packed 4xbf16 epilogue writes.
// ---------------------------------------------------------------------------
struct MoEArgs {
    const float* x_verts;
    const int* gar;
    const int* idx[6];
    const unsigned short* w1t;
    const unsigned short* w2t;
    const unsigned short* w3t;
    const unsigned short* garfb;
    const unsigned short* xvb;   // null -> f32 fallback staging
    float* out;
    int cnt[6];
    int tile_end[6];
};

__global__ __launch_bounds__(256, 4) void moe_kernel(MoEArgs a) {
    __shared__ __align__(16) char smem[32768];
    char* sF = smem;                    // feat 64x384B, then h 64x512B (aliased)

    const int tid = threadIdx.x;
    int bt = blockIdx.x;
    int t = 0;
    while (t < 5 && bt >= a.tile_end[t]) ++t;
    const int tile = bt - (t ? a.tile_end[t - 1] : 0);
    const int cnt = a.cnt[t];
    const int i0 = tile * 64;
    const int* idx = a.idx[t];

    // ---- stage feat tile: 64 rows x 24 16B-units, swizzle u^(row&7) ----
    if (a.xvb) {
        for (int e = tid; e < 1536; e += 256) {
            int m = e / 24, u = e - m * 24;
            int mi = i0 + m; if (mi > cnt - 1) mi = cnt - 1;
            int vid = idx[mi];
            const unsigned short* s16 = (u < 16)
                ? a.xvb + (size_t)vid * 128 + u * 8
                : a.garfb + (size_t)a.gar[vid] * 64 + (u - 16) * 8;
            *(short8*)(sF + m * 384 + ((u ^ (m & 7)) * 16)) = *(const short8*)s16;
        }
    } else {
        for (int e = tid; e < 1536; e += 256) {
            int m = e / 24, u = e - m * 24;
            int mi = i0 + m; if (mi > cnt - 1) mi = cnt - 1;
            int vid = idx[mi];
            short8 pk;
            if (u < 16) {
                const float* src = a.x_verts + (size_t)vid * 128 + u * 8;
                float4 v0 = ((const float4*)src)[0];
                float4 v1 = ((const float4*)src)[1];
                pk[0] = f2bf(v0.x); pk[1] = f2bf(v0.y); pk[2] = f2bf(v0.z); pk[3] = f2bf(v0.w);
                pk[4] = f2bf(v1.x); pk[5] = f2bf(v1.y); pk[6] = f2bf(v1.z); pk[7] = f2bf(v1.w);
            } else {
                pk = *(const short8*)(a.garfb + (size_t)a.gar[vid] * 64 + (u - 16) * 8);
            }
            *(short8*)(sF + m * 384 + ((u ^ (m & 7)) * 16)) = pk;
        }
    }
    __syncthreads();

    const int lane = tid & 63, w = tid >> 6, q = lane >> 4, l = lane & 15;

    // ---- layer 1: H1^T[256 hid][64 v] = W1^T @ F^T, K=192 ----
    float4_ acc[4][4] = {};
    const unsigned short* w1 = a.w1t + (size_t)t * 49152;
    for (int ks = 0; ks < 6; ++ks) {
        short8 af[4], bfr[4];
        for (int mt = 0; mt < 4; ++mt) {
            int hid = w * 64 + mt * 16 + l;
            af[mt] = *(const short8*)(w1 + hid * 192 + ks * 32 + q * 8);
        }
        for (int nt = 0; nt < 4; ++nt) {
            int v = nt * 16 + l;
            bfr[nt] = *(const short8*)(sF + v * 384 + (((ks * 4 + q) ^ (v & 7)) * 16));
        }
        for (int mt = 0; mt < 4; ++mt)
            for (int nt = 0; nt < 4; ++nt)
                acc[mt][nt] = __builtin_amdgcn_mfma_f32_16x16x32_bf16(
                    af[mt], bfr[nt], acc[mt][nt], 0, 0, 0);
    }
    __syncthreads();   // all feat reads done before overwriting sF with h1

    // relu -> h1: row v stride 512B, 16B-unit swizzle ku^(v&7), 8B granule
    for (int mt = 0; mt < 4; ++mt)
        for (int nt = 0; nt < 4; ++nt) {
            int v = nt * 16 + l;
            int hu8 = w * 16 + mt * 4 + q;         // hid/4
            int ku16 = hu8 >> 1, par = hu8 & 1;
            uint2 pk;
            pk.x = (unsigned)f2bf(fmaxf(acc[mt][nt][0], 0.0f)) |
                   ((unsigned)f2bf(fmaxf(acc[mt][nt][1], 0.0f)) << 16);
            pk.y = (unsigned)f2bf(fmaxf(acc[mt][nt][2], 0.0f)) |
                   ((unsigned)f2bf(fmaxf(acc[mt][nt][3], 0.0f)) << 16);
            *(uint2*)(sF + v * 512 + ((ku16 ^ (v & 7)) * 16) + par * 8) = pk;
        }
    __syncthreads();

    // ---- layer 2: H2^T = W2^T @ H1^T, K=256 ----
    float4_ acc2[4][4] = {};
    const unsigned short* w2 = a.w2t + (size_t)t * 65536;
    for (int ks = 0; ks < 8; ++ks) {
        short8 af[4], bfr[4];
        for (int mt = 0; mt < 4; ++mt) {
            int hid = w * 64 + mt * 16 + l;
            af[mt] = *(const short8*)(w2 + hid * 256 + ks * 32 + q * 8);
        }
        for (int nt = 0; nt < 4; ++nt) {
            int v = nt * 16 + l;
            bfr[nt] = *(const short8*)(sF + v * 512 + (((ks * 4 + q) ^ (v & 7)) * 16));
        }
        for (int mt = 0; mt < 4; ++mt)
            for (int nt = 0; nt < 4; ++nt)
                acc2[mt][nt] = __builtin_amdgcn_mfma_f32_16x16x32_bf16(
                    af[mt], bfr[nt], acc2[mt][nt], 0, 0, 0);
    }
    __syncthreads();   // all h1 reads done before in-place overwrite with h2

    for (int mt = 0; mt < 4; ++mt)
        for (int nt = 0; nt < 4; ++nt) {
            int v = nt * 16 + l;
            int hu8 = w * 16 + mt * 4 + q;
            int ku16 = hu8 >> 1, par = hu8 & 1;
            uint2 pk;
            pk.x = (unsigned)f2bf(fmaxf(acc2[mt][nt][0], 0.0f)) |
                   ((unsigned)f2bf(fmaxf(acc2[mt][nt][1], 0.0f)) << 16);
            pk.y = (unsigned)f2bf(fmaxf(acc2[mt][nt][2], 0.0f)) |
                   ((unsigned)f2bf(fmaxf(acc2[mt][nt][3], 0.0f)) << 16);
            *(uint2*)(sF + v * 512 + ((ku16 ^ (v & 7)) * 16) + par * 8) = pk;
        }
    __syncthreads();

    // ---- layer 3: out^T[16(3) x 64v], wave w owns vertex tile w, full K ----
    float4_ acc3 = {};
    const unsigned short* w3 = a.w3t + (size_t)t * 4096;
    int v3 = w * 16 + l;
    for (int ks = 0; ks < 8; ++ks) {
        short8 a3 = *(const short8*)(w3 + l * 256 + ks * 32 + q * 8);
        short8 b3 = *(const short8*)(sF + v3 * 512 + (((ks * 4 + q) ^ (v3 & 7)) * 16));
        acc3 = __builtin_amdgcn_mfma_f32_16x16x32_bf16(a3, b3, acc3, 0, 0, 0);
    }
    // D[m=q*4+r][n=l]: q==0 lanes hold outdims 0..3 for vertex v3
    if (q == 0) {
        int mi = i0 + v3;
        if (mi < cnt) {
            float* o = a.out + (size_t)idx[mi] * 3;
            o[0] = acc3[0]; o[1] = acc3[1]; o[2] = acc3[2];
        }
    }
}

// ---------------------------------------------------------------------------
extern "C" void kernel_launch(void* const* d_in, const int* in_sizes, int n_in,
                              void* d_out, int out_size, void* d_ws, size_t ws_size,
                              hipStream_t stream) {
    const float* imgs    = (const float*)d_in[0];
    const float* pros    = (const float*)d_in[1];
    const float* x_verts = (const float*)d_in[2];
    const float* W1      = (const float*)d_in[3];
    const float* W2      = (const float*)d_in[4];
    const float* W3      = (const float*)d_in[5];
    const int* imgbatch  = (const int*)d_in[6];
    const int* gar       = (const int*)d_in[7];

    // ws layout (16B-aligned): w1t | w2t | w3t | garfb | xvb
    unsigned short* w1t  = (unsigned short*)d_ws;                      // 589824 B
    unsigned short* w2t  = (unsigned short*)((char*)d_ws + 589824);    // 786432 B
    unsigned short* w3t  = (unsigned short*)((char*)d_ws + 1376256);   // 49152 B
    unsigned short* garfb= (unsigned short*)((char*)d_ws + 1425408);   // 3072 B (pad 4096)
    unsigned short* xvb  = (unsigned short*)((char*)d_ws + 1429504);   // 26394624 B
    const size_t ws_need = 1429504u + 26394624u;
    bool has_xvb = ws_size >= ws_need;

    int prep_blocks = GARF_BLOCKS + PREP_BLOCKS + (has_xvb ? XV_BLOCKS : 0);
    prep_garf<<<prep_blocks, 256, 0, stream>>>(
        imgs, pros, imgbatch, W1, W2, W3, x_verts, w1t, w2t, w3t, garfb,
        has_xvb ? xvb : nullptr);

    MoEArgs a;
    a.x_verts = x_verts;
    a.gar = gar;
    for (int t = 0; t < 6; ++t) a.idx[t] = (const int*)d_in[8 + t];
    a.w1t = w1t; a.w2t = w2t; a.w3t = w3t;
    a.garfb = garfb;
    a.xvb = has_xvb ? xvb : nullptr;
    a.out = (float*)d_out;
    int tiles = 0;
    for (int t = 0; t < 6; ++t) {
        a.cnt[t] = in_sizes[8 + t];
        tiles += (a.cnt[t] + 63) / 64;
        a.tile_end[t] = tiles;
    }
    moe_kernel<<<tiles, 256, 0, stream>>>(a);
}

// Round 4
// 277.490 us; speedup vs baseline: 1.0299x; 1.0299x over previous
//
#include <hip/hip_runtime.h>

typedef __attribute__((ext_vector_type(8))) short short8;
typedef __attribute__((ext_vector_type(4))) float float4_;

__device__ __forceinline__ unsigned short f2bf(float f) {
    unsigned u = __float_as_uint(f);
    u += 0x7FFFu + ((u >> 16) & 1u);   // round-to-nearest-even
    return (unsigned short)(u >> 16);
}

#define GARF_BLOCKS 1536   // G(24) * C(64)
#define PREP_BLOCKS 2784   // ceil(712704 / 256)

// ---------------------------------------------------------------------------
// Fused kernel 0: (a) ROI-align 32x32 bilinear patch means -> garf[G][C]
//                 (b) weights fp32 -> bf16, transposed to [N][K]
// ---------------------------------------------------------------------------
__global__ void prep_garf(const float* __restrict__ imgs,
                          const float* __restrict__ pros,
                          const int* __restrict__ imgbatch,
                          const float* __restrict__ W1,
                          const float* __restrict__ W2,
                          const float* __restrict__ W3,
                          unsigned short* __restrict__ w1t,
                          unsigned short* __restrict__ w2t,
                          unsigned short* __restrict__ w3t,
                          float* __restrict__ garf) {
    const int tid = threadIdx.x;
    if (blockIdx.x < GARF_BLOCKS) {
        __shared__ float part[4];
        int pc = blockIdx.x;
        int g = pc >> 6, c = pc & 63;
        int b = imgbatch[g];
        float cx = pros[g * 2 + 0], cy = pros[g * 2 + 1];
        int i = tid >> 3;                 // row 0..31
        int j0 = (tid & 7) * 4;           // 4 columns per thread
        float y = cy - 16.0f + (float)i + 0.5f;
        float yf = floorf(y);
        float wy1 = y - yf, wy0 = 1.0f - wy1;
        int iy0 = min(max((int)yf, 0), 191), iy1 = min(max((int)yf + 1, 0), 191);
        const float* base = imgs + (size_t)(b * 64 + c) * 36864;
        const float* r0 = base + iy0 * 192;
        const float* r1 = base + iy1 * 192;
        float sum = 0.0f;
#pragma unroll
        for (int jj = 0; jj < 4; ++jj) {
            float x = cx - 16.0f + (float)(j0 + jj) + 0.5f;
            float xf = floorf(x);
            float wx1 = x - xf, wx0 = 1.0f - wx1;
            int ix0 = min(max((int)xf, 0), 191), ix1 = min(max((int)xf + 1, 0), 191);
            sum += wy0 * (wx0 * r0[ix0] + wx1 * r0[ix1]) +
                   wy1 * (wx0 * r1[ix0] + wx1 * r1[ix1]);
        }
        for (int s = 32; s >= 1; s >>= 1) sum += __shfl_xor(sum, s);
        if ((tid & 63) == 0) part[tid >> 6] = sum;
        __syncthreads();
        if (tid == 0)
            garf[g * 64 + c] = (part[0] + part[1] + part[2] + part[3]) * (1.0f / 1024.0f);
    } else {
        int id = (blockIdx.x - GARF_BLOCKS) * 256 + tid;
        if (id < 294912) {                       // W1: 6*192*256, src [t][k][n]
            int t = id / 49152, r = id % 49152;
            int k = r >> 8, n = r & 255;
            w1t[t * 49152 + n * 192 + k] = f2bf(W1[id]);
        } else if (id < 688128) {                // W2: 6*256*256
            int i2 = id - 294912;
            int t = i2 >> 16, r = i2 & 65535;
            int k = r >> 8, n = r & 255;
            w2t[t * 65536 + n * 256 + k] = f2bf(W2[i2]);
        } else if (id < 712704) {                // w3t dest: 6*16*256 (n>=3 zero)
            int i3 = id - 688128;
            int t = i3 >> 12, r = i3 & 4095;
            int n = r >> 8, k = r & 255;
            w3t[i3] = (n < 3) ? f2bf(W3[t * 768 + k * 3 + n]) : (unsigned short)0;
        }
    }
}

// ---------------------------------------------------------------------------
// Kernel 1: fused MoE MLP (R0 structure: one 64-vertex tile per 256-thread
// block). Change vs R0: __launch_bounds__(256,3) lifts the 64-VGPR squeeze
// (acc eats 64 AGPRs; at (256,4) the unified 128-reg cap left zero room to
// pipeline loads), and all three ks-loops are software-pipelined with
// distance-1 double-buffered fragments; each layer's first weight fragments
// are pre-issued before the preceding barrier (register-destined global
// loads are barrier-safe and land under the neighboring phase).
// ---------------------------------------------------------------------------
struct MoEArgs {
    const float* x_verts;
    const int* gar;
    const int* idx[6];
    const unsigned short* w1t;
    const unsigned short* w2t;
    const unsigned short* w3t;
    const float* garf;
    float* out;
    int cnt[6];
    int tile_end[6];
};

__global__ __launch_bounds__(256, 3) void moe_kernel(MoEArgs a) {
    __shared__ __align__(16) char smem[32768];
    char* sF = smem;                    // feat 64x384B, then h 64x512B (aliased)

    const int tid = threadIdx.x;
    int bt = blockIdx.x;
    int t = 0;
    while (t < 5 && bt >= a.tile_end[t]) ++t;
    const int tile = bt - (t ? a.tile_end[t - 1] : 0);
    const int cnt = a.cnt[t];
    const int i0 = tile * 64;
    const int* idx = a.idx[t];

    const int lane = tid & 63, w = tid >> 6, q = lane >> 4, l = lane & 15;
    const unsigned short* w1 = a.w1t + (size_t)t * 49152;
    const unsigned short* w2 = a.w2t + (size_t)t * 65536;
    const unsigned short* w3 = a.w3t + (size_t)t * 4096;

    // pre-issue layer-1 ks=0 weight fragments (land during staging)
    short8 a_c[4], a_n[4], b_c[4], b_n[4];
#pragma unroll
    for (int mt = 0; mt < 4; ++mt)
        a_c[mt] = *(const short8*)(w1 + (w * 64 + mt * 16 + l) * 192 + q * 8);

    // ---- stage feat tile: 64 rows x 24 16B-units, swizzle u^(row&7) ----
#pragma unroll
    for (int e0 = 0; e0 < 1536; e0 += 256) {
        int e = e0 + tid;
        int m = e / 24, u = e - m * 24;
        int mi = i0 + m; if (mi > cnt - 1) mi = cnt - 1;
        int vid = idx[mi];
        const float* src = (u < 16)
            ? a.x_verts + (size_t)vid * 128 + u * 8
            : a.garf + (size_t)a.gar[vid] * 64 + (u - 16) * 8;
        float4 v0 = ((const float4*)src)[0];
        float4 v1 = ((const float4*)src)[1];
        short8 pk;
        pk[0] = f2bf(v0.x); pk[1] = f2bf(v0.y); pk[2] = f2bf(v0.z); pk[3] = f2bf(v0.w);
        pk[4] = f2bf(v1.x); pk[5] = f2bf(v1.y); pk[6] = f2bf(v1.z); pk[7] = f2bf(v1.w);
        *(short8*)(sF + m * 384 + ((u ^ (m & 7)) * 16)) = pk;
    }
    __syncthreads();

    // ---- layer 1: H1^T[256 hid][64 v] = W1^T @ F^T, K=192, pipelined ----
    float4_ acc[4][4] = {};
#pragma unroll
    for (int nt = 0; nt < 4; ++nt) {
        int v = nt * 16 + l;
        b_c[nt] = *(const short8*)(sF + v * 384 + ((q ^ (v & 7)) * 16));
    }
#pragma unroll
    for (int ks = 0; ks < 6; ++ks) {
        if (ks + 1 < 6) {
#pragma unroll
            for (int mt = 0; mt < 4; ++mt)
                a_n[mt] = *(const short8*)(w1 + (w * 64 + mt * 16 + l) * 192 + (ks + 1) * 32 + q * 8);
#pragma unroll
            for (int nt = 0; nt < 4; ++nt) {
                int v = nt * 16 + l;
                b_n[nt] = *(const short8*)(sF + v * 384 + ((((ks + 1) * 4 + q) ^ (v & 7)) * 16));
            }
        }
#pragma unroll
        for (int mt = 0; mt < 4; ++mt)
#pragma unroll
            for (int nt = 0; nt < 4; ++nt)
                acc[mt][nt] = __builtin_amdgcn_mfma_f32_16x16x32_bf16(
                    a_c[mt], b_c[nt], acc[mt][nt], 0, 0, 0);
        if (ks + 1 < 6) {
#pragma unroll
            for (int r = 0; r < 4; ++r) { a_c[r] = a_n[r]; b_c[r] = b_n[r]; }
        }
    }
    // pre-issue layer-2 ks=0 weight fragments (land during EPI1)
#pragma unroll
    for (int mt = 0; mt < 4; ++mt)
        a_c[mt] = *(const short8*)(w2 + (w * 64 + mt * 16 + l) * 256 + q * 8);
    __syncthreads();   // all feat reads done before overwriting sF with h1

    // relu -> h1: row v stride 512B, 16B-unit swizzle ku^(v&7), 8B granule
#pragma unroll
    for (int mt = 0; mt < 4; ++mt)
#pragma unroll
        for (int nt = 0; nt < 4; ++nt) {
            int v = nt * 16 + l;
            int hu8 = w * 16 + mt * 4 + q;         // hid/4
            int ku16 = hu8 >> 1, par = hu8 & 1;
            uint2 pk;
            pk.x = (unsigned)f2bf(fmaxf(acc[mt][nt][0], 0.0f)) |
                   ((unsigned)f2bf(fmaxf(acc[mt][nt][1], 0.0f)) << 16);
            pk.y = (unsigned)f2bf(fmaxf(acc[mt][nt][2], 0.0f)) |
                   ((unsigned)f2bf(fmaxf(acc[mt][nt][3], 0.0f)) << 16);
            *(uint2*)(sF + v * 512 + ((ku16 ^ (v & 7)) * 16) + par * 8) = pk;
        }
    __syncthreads();

    // ---- layer 2: H2^T = W2^T @ H1^T, K=256, pipelined ----
    float4_ acc2[4][4] = {};
#pragma unroll
    for (int nt = 0; nt < 4; ++nt) {
        int v = nt * 16 + l;
        b_c[nt] = *(const short8*)(sF + v * 512 + ((q ^ (v & 7)) * 16));
    }
#pragma unroll
    for (int ks = 0; ks < 8; ++ks) {
        if (ks + 1 < 8) {
#pragma unroll
            for (int mt = 0; mt < 4; ++mt)
                a_n[mt] = *(const short8*)(w2 + (w * 64 + mt * 16 + l) * 256 + (ks + 1) * 32 + q * 8);
#pragma unroll
            for (int nt = 0; nt < 4; ++nt) {
                int v = nt * 16 + l;
                b_n[nt] = *(const short8*)(sF + v * 512 + ((((ks + 1) * 4 + q) ^ (v & 7)) * 16));
            }
        }
#pragma unroll
        for (int mt = 0; mt < 4; ++mt)
#pragma unroll
            for (int nt = 0; nt < 4; ++nt)
                acc2[mt][nt] = __builtin_amdgcn_mfma_f32_16x16x32_bf16(
                    a_c[mt], b_c[nt], acc2[mt][nt], 0, 0, 0);
        if (ks + 1 < 8) {
#pragma unroll
            for (int r = 0; r < 4; ++r) { a_c[r] = a_n[r]; b_c[r] = b_n[r]; }
        }
    }
    // pre-issue layer-3 ks=0 weight fragment (lands during EPI2)
    short8 a3_c = *(const short8*)(w3 + l * 256 + q * 8);
    __syncthreads();   // all h1 reads done before in-place overwrite with h2

#pragma unroll
    for (int mt = 0; mt < 4; ++mt)
#pragma unroll
        for (int nt = 0; nt < 4; ++nt) {
            int v = nt * 16 + l;
            int hu8 = w * 16 + mt * 4 + q;
            int ku16 = hu8 >> 1, par = hu8 & 1;
            uint2 pk;
            pk.x = (unsigned)f2bf(fmaxf(acc2[mt][nt][0], 0.0f)) |
                   ((unsigned)f2bf(fmaxf(acc2[mt][nt][1], 0.0f)) << 16);
            pk.y = (unsigned)f2bf(fmaxf(acc2[mt][nt][2], 0.0f)) |
                   ((unsigned)f2bf(fmaxf(acc2[mt][nt][3], 0.0f)) << 16);
            *(uint2*)(sF + v * 512 + ((ku16 ^ (v & 7)) * 16) + par * 8) = pk;
        }
    __syncthreads();

    // ---- layer 3: out^T[16(3) x 64v], wave w owns vertex tile w, pipelined ----
    float4_ acc3 = {};
    int v3 = w * 16 + l;
    short8 b3_c = *(const short8*)(sF + v3 * 512 + ((q ^ (v3 & 7)) * 16));
#pragma unroll
    for (int ks = 0; ks < 8; ++ks) {
        short8 a3_n, b3_n;
        if (ks + 1 < 8) {
            a3_n = *(const short8*)(w3 + l * 256 + (ks + 1) * 32 + q * 8);
            b3_n = *(const short8*)(sF + v3 * 512 + ((((ks + 1) * 4 + q) ^ (v3 & 7)) * 16));
        }
        acc3 = __builtin_amdgcn_mfma_f32_16x16x32_bf16(a3_c, b3_c, acc3, 0, 0, 0);
        if (ks + 1 < 8) { a3_c = a3_n; b3_c = b3_n; }
    }
    // D[m=q*4+r][n=l]: q==0 lanes hold outdims 0..3 for vertex v3
    if (q == 0) {
        int mi = i0 + v3;
        if (mi < cnt) {
            float* o = a.out + (size_t)idx[mi] * 3;
            o[0] = acc3[0]; o[1] = acc3[1]; o[2] = acc3[2];
        }
    }
}

// ---------------------------------------------------------------------------
extern "C" void kernel_launch(void* const* d_in, const int* in_sizes, int n_in,
                              void* d_out, int out_size, void* d_ws, size_t ws_size,
                              hipStream_t stream) {
    const float* imgs    = (const float*)d_in[0];
    const float* pros    = (const float*)d_in[1];
    const float* x_verts = (const float*)d_in[2];
    const float* W1      = (const float*)d_in[3];
    const float* W2      = (const float*)d_in[4];
    const float* W3      = (const float*)d_in[5];
    const int* imgbatch  = (const int*)d_in[6];
    const int* gar       = (const int*)d_in[7];

    // ws layout (16B-aligned): w1t | w2t | w3t | garf
    unsigned short* w1t = (unsigned short*)d_ws;                       // 589824 B
    unsigned short* w2t = (unsigned short*)((char*)d_ws + 589824);     // 786432 B
    unsigned short* w3t = (unsigned short*)((char*)d_ws + 1376256);    // 49152 B
    float* garf         = (float*)((char*)d_ws + 1425408);             // 6144 B

    prep_garf<<<GARF_BLOCKS + PREP_BLOCKS, 256, 0, stream>>>(
        imgs, pros, imgbatch, W1, W2, W3, w1t, w2t, w3t, garf);

    MoEArgs a;
    a.x_verts = x_verts;
    a.gar = gar;
    for (int t = 0; t < 6; ++t) a.idx[t] = (const int*)d_in[8 + t];
    a.w1t = w1t; a.w2t = w2t; a.w3t = w3t;
    a.garf = garf;
    a.out = (float*)d_out;
    int tiles = 0;
    for (int t = 0; t < 6; ++t) {
        a.cnt[t] = in_sizes[8 + t];
        tiles += (a.cnt[t] + 63) / 64;
        a.tile_end[t] = tiles;
    }
    moe_kernel<<<tiles, 256, 0, stream>>>(a);
}